// Round 1
// baseline (313.884 us; speedup 1.0000x reference)
//
#include <hip/hip_runtime.h>

#define NSTEPS 730
#define NGRID  10000
#define LENF   15
#define NEARZERO 1e-5f
#define KB 10           // steps per unrolled block
#define NBLK 73         // 730 = 73 * 10

struct F3 { float p, t, e; };  // (prcp, tmean, pet), 12B

// Fully fused single-wave kernel: one wave = 64 cells, each lane runs the
// entire 730-step HBV recurrence (snow chain + soil/runoff chain + gamma-FIR
// routing) for one cell, with no LDS and no barriers. The loop-carried soil
// chain (~16 dependent ops, 4 transcendentals) is the wall-clock floor; the
// snow chain of future steps and the 15-tap FIR are independent of it and
// issue in its stall shadows across the 10-step unrolled block. Input blocks
// are double-buffered in registers, prefetched one block (~1400 compute
// cycles) ahead of use to hide ~900-cycle HBM latency.
__global__ __launch_bounds__(64, 1) void hbv_fused(const float* __restrict__ xp,
                                                   const float* __restrict__ ps,
                                                   float* __restrict__ out) {
    const int lane = threadIdx.x;
    int g = blockIdx.x * 64 + lane;
    g = (g < NGRID) ? g : (NGRID - 1);    // clamp: dup work on last wg, benign
    const int pb = g * 16;
    const F3* __restrict__ xv = (const F3*)xp;

    // ---- snow params ----
    const float aTT        = ps[pb + 8]  * 5.0f - 2.5f;
    const float aCFMAX     = ps[pb + 9]  * 9.5f + 0.5f;
    const float aCFRxCFMAX = (ps[pb + 10] * 0.1f) * aCFMAX;
    const float aCWH       = ps[pb + 11] * 0.2f;
    // ---- soil params ----
    const float bFC     = ps[pb + 1]  * 950.0f + 50.0f;
    const float bBETA   = ps[pb + 0]  * 5.0f   + 1.0f;
    const float LP      = ps[pb + 5]  * 0.8f   + 0.2f;
    const float bBETAET = ps[pb + 12] * 4.7f   + 0.3f;
    const float bInvFC  = 1.0f / bFC;
    // fold the argument scaling into the log: log2(x/FC)=log2(x)-log2(FC)
    const float bB1 = -bBETA   * __builtin_amdgcn_logf(bFC);
    const float bB2 = -bBETAET * __builtin_amdgcn_logf(LP * bFC);
    const float bC    = ps[pb + 13];
    const float bPERC = ps[pb + 6] * 10.0f;
    const float bK0   = ps[pb + 2] * 0.85f  + 0.05f;
    const float bK1   = ps[pb + 3] * 0.49f  + 0.01f;
    const float bK2   = ps[pb + 4] * 0.199f + 0.001f;
    const float bUZL  = ps[pb + 7] * 100.0f;
    // ---- routing weights: -lgamma(aa)-aa*log(theta) cancel under norm ----
    float w[LENF];
    {
        const float LOG2E = 1.4426950408889634f;
        float aa    = fmaxf(ps[pb + 14] * 2.9f, 0.0f) + 0.1f;
        float theta = fmaxf(ps[pb + 15] * 6.5f, 0.0f) + 0.5f;
        float sc = LOG2E / theta, am1 = aa - 1.0f, wsum = 0.0f;
#pragma unroll
        for (int k = 0; k < LENF; ++k) {
            float tg = (float)k + 0.5f;
            w[k] = __builtin_amdgcn_exp2f(am1 * __builtin_amdgcn_logf(tg) - tg * sc);
            wsum += w[k];
        }
        float inv = 1.0f / wsum;
#pragma unroll
        for (int k = 0; k < LENF; ++k) w[k] *= inv;
    }
    float r[LENF - 1];
#pragma unroll
    for (int j = 0; j < LENF - 1; ++j) r[j] = 0.0f;

    // ---- model state ----
    float snow = NEARZERO, melt = NEARZERO;
    float sm = NEARZERO, suz = NEARZERO, slz = NEARZERO;

    // one KB-step block; identical op order to the verified pipeline kernel
    auto run_block = [&](const F3* in, int base) {
#pragma unroll
        for (int i = 0; i < KB; ++i) {
            // snow chain (carried: snow, melt — independent of soil chain)
            float p = in[i].p, tm = in[i].t, pe = in[i].e;
            float rain = (tm >= aTT) ? p : 0.0f;
            float mm = fmaxf(aCFMAX * (tm - aTT), 0.0f);
            float rr = fmaxf(aCFRxCFMAX * (aTT - tm), 0.0f);
            snow += p - rain;
            float m = fminf(mm, snow);
            melt += m; snow -= m;
            float refr = fminf(rr, melt);
            snow += refr; melt -= refr;
            float tosoil = fmaxf(fmaf(-aCWH, snow, melt), 0.0f);
            melt -= tosoil;
            float rt = rain + tosoil;

            // soil/runoff chain (the irreducible serial core)
            float l1  = __builtin_amdgcn_logf(sm);
            float sw  = fminf(__builtin_amdgcn_exp2f(fmaf(bBETA, l1, bB1)), 1.0f);
            float smp = sm + rt;
            float sm1 = fmaf(-rt, sw, smp);
            float rch = rt * sw;
            float sm2 = fminf(sm1, bFC);
            float exc = fmaxf(sm1 - bFC, 0.0f);
            float l2  = __builtin_amdgcn_logf(sm2);
            float ef  = fminf(__builtin_amdgcn_exp2f(fmaf(bBETAET, l2, bB2)), 1.0f);
            float sm3 = fmaxf(fmaf(-pe, ef, sm2), NEARZERO);
            float d   = fmaxf(fmaf(-bInvFC, sm3, 1.0f), 0.0f);
            float cz  = bC * slz;
            float cap = fminf(slz, cz * d);
            sm = sm3 + cap;
            float slz1 = fmaxf(slz - cap, NEARZERO);
            float su1 = suz + rch + exc;
            float pa  = fminf(su1, bPERC);
            float su2 = su1 - pa;
            float q0  = bK0 * fmaxf(su2 - bUZL, 0.0f);
            float su3 = su2 - q0;
            float q1  = bK1 * su3;
            suz = su3 - q1;
            float sl2 = slz1 + pa;
            float q2  = bK2 * sl2;
            slz = sl2 - q2;
            float q = (q0 + q1) + q2;

            // transposed-FIR gamma routing + store (independent of soil chain)
            out[(size_t)(base + i) * NGRID + g] = fmaf(w[0], q, r[0]);
#pragma unroll
            for (int j = 0; j < LENF - 2; ++j)
                r[j] = fmaf(w[j + 1], q, r[j + 1]);
            r[LENF - 2] = w[LENF - 1] * q;
        }
    };

    // register-resident double-buffered input blocks
    F3 bufA[KB], bufB[KB];
#pragma unroll
    for (int i = 0; i < KB; ++i) bufA[i] = xv[(size_t)i * NGRID + g];

    for (int n = 0; n < NBLK; n += 2) {
        if (n + 1 < NBLK) {
#pragma unroll
            for (int i = 0; i < KB; ++i)
                bufB[i] = xv[(size_t)((n + 1) * KB + i) * NGRID + g];
        }
        run_block(bufA, n * KB);
        if (n + 1 < NBLK) {
            if (n + 2 < NBLK) {
#pragma unroll
                for (int i = 0; i < KB; ++i)
                    bufA[i] = xv[(size_t)((n + 2) * KB + i) * NGRID + g];
            }
            run_block(bufB, (n + 1) * KB);
        }
    }
}

extern "C" void kernel_launch(void* const* d_in, const int* in_sizes, int n_in,
                              void* d_out, int out_size, void* d_ws, size_t ws_size,
                              hipStream_t stream) {
    const float* x_phy      = (const float*)d_in[0]; // f32 (730,10000,3)
    const float* phy_static = (const float*)d_in[1]; // f32 (10000,16)
    float* out = (float*)d_out;                      // f32 (730,10000)

    int nwg = (NGRID + 63) / 64;  // 157 workgroups x 64 threads, 1 wave each
    hbv_fused<<<nwg, 64, 0, stream>>>(x_phy, phy_static, out);
}

// Round 4
// 278.066 us; speedup vs baseline: 1.1288x; 1.1288x over previous
//
#include <hip/hip_runtime.h>

#define NSTEPS 730
#define NGRID  10000
#define LENF   15
#define NEARZERO 1e-5f
#define KB 10           // steps per block
#define NBLK 73         // 730 = 73 * 10

struct F3 { float p, t, e; };  // (prcp, tmean, pet), 12B

// Fused single-wave kernel, register-double-buffered inputs, pinned schedule.
// One wave = 64 cells; each lane runs the whole 730-step HBV recurrence.
//
// History: round 1 (this structure, no fences) PASSED at 217us but the
// compiler sank the prefetch loads to just-in-time (VGPR=80), exposing
// ~500cy/step of memory latency. Rounds 2-3 (global_load_lds size=12
// staging) failed with identical deterministic garbage -> the unmeasured
// size=12 LDS-DMA path is the suspect; abandoned. This round: keep the
// verified register path, pin each LOAD/COMPUTE section with
// sched_barrier(0) (proven to survive compilation in rounds 2-3) so the
// prefetch cannot be sunk, and let the compiler's automatic waitcnt
// insertion provide correctness (it tracks exact outstanding vmem counts;
// the first use of block n+2's registers is one full block compute ~1400cy
// after issue, so the auto-wait is free).
__global__ __launch_bounds__(64, 1) void hbv_fused(const float* __restrict__ xp,
                                                   const float* __restrict__ ps,
                                                   float* __restrict__ out) {
    const int lane = threadIdx.x;
    int g = blockIdx.x * 64 + lane;
    g = (g < NGRID) ? g : (NGRID - 1);    // clamp: dup work on last wg, benign
    const int pb = g * 16;
    const F3* __restrict__ xv = (const F3*)xp;

    // ---- snow params ----
    const float aTT        = ps[pb + 8]  * 5.0f - 2.5f;
    const float aCFMAX     = ps[pb + 9]  * 9.5f + 0.5f;
    const float aCFRxCFMAX = (ps[pb + 10] * 0.1f) * aCFMAX;
    const float aCWH       = ps[pb + 11] * 0.2f;
    // ---- soil params ----
    const float bFC     = ps[pb + 1]  * 950.0f + 50.0f;
    const float bBETA   = ps[pb + 0]  * 5.0f   + 1.0f;
    const float LP      = ps[pb + 5]  * 0.8f   + 0.2f;
    const float bBETAET = ps[pb + 12] * 4.7f   + 0.3f;
    const float bInvFC  = 1.0f / bFC;
    // fold argument scaling into the log: log2(x/FC) = log2(x) - log2(FC)
    const float bB1 = -bBETA   * __builtin_amdgcn_logf(bFC);
    const float bB2 = -bBETAET * __builtin_amdgcn_logf(LP * bFC);
    const float bC    = ps[pb + 13];
    const float bPERC = ps[pb + 6] * 10.0f;
    const float bK0   = ps[pb + 2] * 0.85f  + 0.05f;
    const float bK1   = ps[pb + 3] * 0.49f  + 0.01f;
    const float bK2   = ps[pb + 4] * 0.199f + 0.001f;
    const float bUZL  = ps[pb + 7] * 100.0f;
    // ---- routing weights: -lgamma(aa)-aa*log(theta) cancel under norm ----
    float w[LENF];
    {
        const float LOG2E = 1.4426950408889634f;
        float aa    = fmaxf(ps[pb + 14] * 2.9f, 0.0f) + 0.1f;
        float theta = fmaxf(ps[pb + 15] * 6.5f, 0.0f) + 0.5f;
        float sc = LOG2E / theta, am1 = aa - 1.0f, wsum = 0.0f;
#pragma unroll
        for (int k = 0; k < LENF; ++k) {
            float tg = (float)k + 0.5f;
            w[k] = __builtin_amdgcn_exp2f(am1 * __builtin_amdgcn_logf(tg) - tg * sc);
            wsum += w[k];
        }
        float inv = 1.0f / wsum;
#pragma unroll
        for (int k = 0; k < LENF; ++k) w[k] *= inv;
    }
    float r[LENF - 1];
#pragma unroll
    for (int j = 0; j < LENF - 1; ++j) r[j] = 0.0f;

    // ---- model state ----
    float snow = NEARZERO, melt = NEARZERO;
    float sm = NEARZERO, suz = NEARZERO, slz = NEARZERO;

    F3 A[KB], B[KB];

    auto LOAD = [&](F3* buf, int blk) {
#pragma unroll
        for (int i = 0; i < KB; ++i)
            buf[i] = xv[(size_t)(blk * KB + i) * NGRID + g];
    };

    // one KB-step block; arithmetic identical to all passing rounds
    auto COMPUTE = [&](const F3* in, int n) {
#pragma unroll
        for (int i = 0; i < KB; ++i) {
            // snow chain (carried: snow, melt — independent of soil chain)
            float p = in[i].p, tm = in[i].t, pe = in[i].e;
            float rain = (tm >= aTT) ? p : 0.0f;
            float mm = fmaxf(aCFMAX * (tm - aTT), 0.0f);
            float rr = fmaxf(aCFRxCFMAX * (aTT - tm), 0.0f);
            snow += p - rain;
            float m = fminf(mm, snow);
            melt += m; snow -= m;
            float refr = fminf(rr, melt);
            snow += refr; melt -= refr;
            float tosoil = fmaxf(fmaf(-aCWH, snow, melt), 0.0f);
            melt -= tosoil;
            float rt = rain + tosoil;

            // soil/runoff chain (the irreducible serial core)
            float l1  = __builtin_amdgcn_logf(sm);
            float sw  = fminf(__builtin_amdgcn_exp2f(fmaf(bBETA, l1, bB1)), 1.0f);
            float smp = sm + rt;
            float sm1 = fmaf(-rt, sw, smp);
            float rch = rt * sw;
            float sm2 = fminf(sm1, bFC);
            float exc = fmaxf(sm1 - bFC, 0.0f);
            float l2  = __builtin_amdgcn_logf(sm2);
            float ef  = fminf(__builtin_amdgcn_exp2f(fmaf(bBETAET, l2, bB2)), 1.0f);
            float sm3 = fmaxf(fmaf(-pe, ef, sm2), NEARZERO);
            float d   = fmaxf(fmaf(-bInvFC, sm3, 1.0f), 0.0f);
            float cz  = bC * slz;
            float cap = fminf(slz, cz * d);
            sm = sm3 + cap;
            float slz1 = fmaxf(slz - cap, NEARZERO);
            float su1 = suz + rch + exc;
            float pa  = fminf(su1, bPERC);
            float su2 = su1 - pa;
            float q0  = bK0 * fmaxf(su2 - bUZL, 0.0f);
            float su3 = su2 - q0;
            float q1  = bK1 * su3;
            suz = su3 - q1;
            float sl2 = slz1 + pa;
            float q2  = bK2 * sl2;
            slz = sl2 - q2;
            float q = (q0 + q1) + q2;

            // transposed-FIR gamma routing + store (independent of soil chain)
            out[(size_t)(n * KB + i) * NGRID + g] = fmaf(w[0], q, r[0]);
#pragma unroll
            for (int j = 0; j < LENF - 2; ++j)
                r[j] = fmaf(w[j + 1], q, r[j + 1]);
            r[LENF - 2] = w[LENF - 1] * q;
        }
    };

    // prologue: both buffers in flight before any compute
    __builtin_amdgcn_sched_barrier(0);
    LOAD(A, 0);
    __builtin_amdgcn_sched_barrier(0);
    LOAD(B, 1);
    __builtin_amdgcn_sched_barrier(0);

    // hot loop: n = 0,2,...,68 — every section pinned, loads always present
    for (int n = 0; n + 3 < NBLK; n += 2) {
        COMPUTE(A, n);
        __builtin_amdgcn_sched_barrier(0);
        LOAD(A, n + 2);                       // first use: one block later
        __builtin_amdgcn_sched_barrier(0);
        COMPUTE(B, n + 1);
        __builtin_amdgcn_sched_barrier(0);
        LOAD(B, n + 3);
        __builtin_amdgcn_sched_barrier(0);
    }
    // epilogue: blocks 70, 71, 72 (A holds 70, B holds 71 after the loop)
    COMPUTE(A, 70);
    __builtin_amdgcn_sched_barrier(0);
    LOAD(A, 72);
    __builtin_amdgcn_sched_barrier(0);
    COMPUTE(B, 71);
    __builtin_amdgcn_sched_barrier(0);
    COMPUTE(A, 72);
}

extern "C" void kernel_launch(void* const* d_in, const int* in_sizes, int n_in,
                              void* d_out, int out_size, void* d_ws, size_t ws_size,
                              hipStream_t stream) {
    const float* x_phy      = (const float*)d_in[0]; // f32 (730,10000,3)
    const float* phy_static = (const float*)d_in[1]; // f32 (10000,16)
    float* out = (float*)d_out;                      // f32 (730,10000)

    int nwg = (NGRID + 63) / 64;  // 157 workgroups x 64 threads, 1 wave each
    hbv_fused<<<nwg, 64, 0, stream>>>(x_phy, phy_static, out);
}

// Round 6
// 211.654 us; speedup vs baseline: 1.4830x; 1.3138x over previous
//
#include <hip/hip_runtime.h>

#define NSTEPS 730
#define NGRID  10000
#define LENF   15
#define NEARZERO 1e-5f
#define KB 10           // steps per block
#define NBLK 73         // 730 = 73 * 10

struct F3 { float p, t, e; };  // (prcp, tmean, pet), 12B

// Compiler-level memory fence: zero instructions, but IR alias analysis must
// assume it reads+writes memory, so global loads CANNOT be sunk across it.
// This is what sched_barrier(0) failed to provide in round 4 (IntrNoMem at
// IR level -> IR sinking moved the prefetch loads to their uses, VGPR=80,
// ~500cy exposed latency per step). Unlike rounds 2/3/5 (global_load_lds
// size=12 / inline-asm raw loads + hand vmcnt ledger -> garbage / crash),
// the loads here stay compiler-visible, so SIInsertWaitcnts keeps exact and
// automatic vmcnt bookkeeping: at first use of buffer A it waits only for
// A's 10 loads, leaving B's 10 in flight. Correct by construction.
#define MEMFENCE() asm volatile("" ::: "memory")

// Fused single-wave kernel, register-double-buffered inputs, fence-pinned
// prefetch. One wave = 64 cells; each lane runs the whole 730-step HBV
// recurrence (snow chain + soil chain + gamma-FIR routing). Wall time is
// single-wave serial time (157 wgs run concurrently; occupancy is
// irrelevant), so the only lever is per-step cost: ~50 VALU ops (~100cy
// issue) + 4 transcendentals, soil dependency chain ~130cy. Loads for block
// n+2 are issued one full block (~1300cy) before first use -> HBM latency
// fully hidden behind compute.
__global__ __launch_bounds__(64, 1) void hbv_fused(const float* __restrict__ xp,
                                                   const float* __restrict__ ps,
                                                   float* __restrict__ out) {
    const int lane = threadIdx.x;
    int g = blockIdx.x * 64 + lane;
    g = (g < NGRID) ? g : (NGRID - 1);    // clamp: dup work on last wg, benign
    const int pb = g * 16;
    const F3* __restrict__ xv = (const F3*)xp;

    // ---- snow params ----
    const float aTT        = ps[pb + 8]  * 5.0f - 2.5f;
    const float aCFMAX     = ps[pb + 9]  * 9.5f + 0.5f;
    const float aCFRxCFMAX = (ps[pb + 10] * 0.1f) * aCFMAX;
    const float aCWH       = ps[pb + 11] * 0.2f;
    // ---- soil params ----
    const float bFC     = ps[pb + 1]  * 950.0f + 50.0f;
    const float bBETA   = ps[pb + 0]  * 5.0f   + 1.0f;
    const float LP      = ps[pb + 5]  * 0.8f   + 0.2f;
    const float bBETAET = ps[pb + 12] * 4.7f   + 0.3f;
    const float bInvFC  = 1.0f / bFC;
    // fold argument scaling into the log: log2(x/FC) = log2(x) - log2(FC)
    const float bB1 = -bBETA   * __builtin_amdgcn_logf(bFC);
    const float bB2 = -bBETAET * __builtin_amdgcn_logf(LP * bFC);
    const float bC    = ps[pb + 13];
    const float bPERC = ps[pb + 6] * 10.0f;
    const float bK0   = ps[pb + 2] * 0.85f  + 0.05f;
    const float bK1   = ps[pb + 3] * 0.49f  + 0.01f;
    const float bK2   = ps[pb + 4] * 0.199f + 0.001f;
    const float bUZL  = ps[pb + 7] * 100.0f;
    // ---- routing weights: -lgamma(aa)-aa*log(theta) cancel under norm ----
    float w[LENF];
    {
        const float LOG2E = 1.4426950408889634f;
        float aa    = fmaxf(ps[pb + 14] * 2.9f, 0.0f) + 0.1f;
        float theta = fmaxf(ps[pb + 15] * 6.5f, 0.0f) + 0.5f;
        float sc = LOG2E / theta, am1 = aa - 1.0f, wsum = 0.0f;
#pragma unroll
        for (int k = 0; k < LENF; ++k) {
            float tg = (float)k + 0.5f;
            w[k] = __builtin_amdgcn_exp2f(am1 * __builtin_amdgcn_logf(tg) - tg * sc);
            wsum += w[k];
        }
        float inv = 1.0f / wsum;
#pragma unroll
        for (int k = 0; k < LENF; ++k) w[k] *= inv;
    }
    float r[LENF - 1];
#pragma unroll
    for (int j = 0; j < LENF - 1; ++j) r[j] = 0.0f;

    // ---- model state ----
    float snow = NEARZERO, melt = NEARZERO;
    float sm = NEARZERO, suz = NEARZERO, slz = NEARZERO;

    F3 A[KB], B[KB];

    auto LOAD = [&](F3* buf, int blk) {
#pragma unroll
        for (int i = 0; i < KB; ++i)
            buf[i] = xv[(size_t)(blk * KB + i) * NGRID + g];
    };

    // one KB-step block; arithmetic identical to all passing rounds
    auto COMPUTE = [&](const F3* in, int n) {
#pragma unroll
        for (int i = 0; i < KB; ++i) {
            // snow chain (carried: snow, melt — independent of soil chain)
            float p = in[i].p, tm = in[i].t, pe = in[i].e;
            float rain = (tm >= aTT) ? p : 0.0f;
            float mm = fmaxf(aCFMAX * (tm - aTT), 0.0f);
            float rr = fmaxf(aCFRxCFMAX * (aTT - tm), 0.0f);
            snow += p - rain;
            float m = fminf(mm, snow);
            melt += m; snow -= m;
            float refr = fminf(rr, melt);
            snow += refr; melt -= refr;
            float tosoil = fmaxf(fmaf(-aCWH, snow, melt), 0.0f);
            melt -= tosoil;
            float rt = rain + tosoil;

            // soil/runoff chain (the irreducible serial core)
            float l1  = __builtin_amdgcn_logf(sm);
            float sw  = fminf(__builtin_amdgcn_exp2f(fmaf(bBETA, l1, bB1)), 1.0f);
            float smp = sm + rt;
            float sm1 = fmaf(-rt, sw, smp);
            float rch = rt * sw;
            float sm2 = fminf(sm1, bFC);
            float exc = fmaxf(sm1 - bFC, 0.0f);
            float l2  = __builtin_amdgcn_logf(sm2);
            float ef  = fminf(__builtin_amdgcn_exp2f(fmaf(bBETAET, l2, bB2)), 1.0f);
            float sm3 = fmaxf(fmaf(-pe, ef, sm2), NEARZERO);
            float d   = fmaxf(fmaf(-bInvFC, sm3, 1.0f), 0.0f);
            float cz  = bC * slz;
            float cap = fminf(slz, cz * d);
            sm = sm3 + cap;
            float slz1 = fmaxf(slz - cap, NEARZERO);
            float su1 = suz + rch + exc;
            float pa  = fminf(su1, bPERC);
            float su2 = su1 - pa;
            float q0  = bK0 * fmaxf(su2 - bUZL, 0.0f);
            float su3 = su2 - q0;
            float q1  = bK1 * su3;
            suz = su3 - q1;
            float sl2 = slz1 + pa;
            float q2  = bK2 * sl2;
            slz = sl2 - q2;
            float q = (q0 + q1) + q2;

            // transposed-FIR gamma routing + store (independent of soil chain)
            out[(size_t)(n * KB + i) * NGRID + g] = fmaf(w[0], q, r[0]);
#pragma unroll
            for (int j = 0; j < LENF - 2; ++j)
                r[j] = fmaf(w[j + 1], q, r[j + 1]);
            r[LENF - 2] = w[LENF - 1] * q;
        }
    };

    // prologue: blocks 0 and 1 in flight before any compute
    MEMFENCE();
    LOAD(A, 0);
    MEMFENCE();
    LOAD(B, 1);
    MEMFENCE();

    // hot loop: n = 0,2,...,68 — loads fence-pinned in their section
    for (int n = 0; n + 3 < NBLK; n += 2) {
        COMPUTE(A, n);
        MEMFENCE();
        LOAD(A, n + 2);                       // first use: one block later
        MEMFENCE();
        COMPUTE(B, n + 1);
        MEMFENCE();
        LOAD(B, n + 3);
        MEMFENCE();
    }
    // epilogue: blocks 70, 71, 72 (A holds 70, B holds 71 after the loop)
    COMPUTE(A, 70);
    MEMFENCE();
    LOAD(A, 72);
    MEMFENCE();
    COMPUTE(B, 71);
    MEMFENCE();
    COMPUTE(A, 72);
}

extern "C" void kernel_launch(void* const* d_in, const int* in_sizes, int n_in,
                              void* d_out, int out_size, void* d_ws, size_t ws_size,
                              hipStream_t stream) {
    const float* x_phy      = (const float*)d_in[0]; // f32 (730,10000,3)
    const float* phy_static = (const float*)d_in[1]; // f32 (10000,16)
    float* out = (float*)d_out;                      // f32 (730,10000)

    int nwg = (NGRID + 63) / 64;  // 157 workgroups x 64 threads, 1 wave each
    hbv_fused<<<nwg, 64, 0, stream>>>(x_phy, phy_static, out);
}

// Round 7
// 201.806 us; speedup vs baseline: 1.5554x; 1.0488x over previous
//
#include <hip/hip_runtime.h>

#define NSTEPS 730
#define NGRID  10000
#define LENF   15
#define NEARZERO 1e-5f
#define KB 10            // steps per pipeline block
#define NBLK 73          // 730 = 73 * 10
#define NROUND (NBLK + 4)

struct F3 { float p, t, e; };  // (prcp, tmean, pet), 12B

// 3-role software pipeline (round-0 skeleton) with both memory-latency leaks
// fixed. One workgroup = 192 threads = 3 waves handling 64 cells.
//   Wave A: batch input prefetch (reg double-buffer) + snow chain -> LDS
//   Wave B: soil/runoff chain (irreducible serial core)          -> LDS
//   Wave C: transposed-FIR gamma routing, stores DELAYED one round
//
// Why this beats both ancestors:
//  - round 6 (fused single wave) is ISSUE-bound: ~78% per-SIMD issue
//    occupancy, ~295 cy/step of VALU issue. Splitting 3 ways caps the
//    critical role (soil) at ~110 cy/step of issue.
//  - round 0 (original pipeline) lost ~3000 cy/round to JIT-sunk input
//    loads (10 serialized latencies) + store drain at the barrier.
//    Fixes: (1) A loads block m into a register double-buffer at round
//    START (10 parallel loads, consumed next round; __syncthreads pins
//    them — loads cannot sink across a workgroup fence — and the barrier
//    drain is free because they are ~1300cy old by then). (2) C buffers
//    its 10 outputs in registers and stores them at the START of the
//    NEXT round, so the barrier drains ~1300cy-old stores, not fresh ones.
//
// Skew: A loads block m @ round m; A snow-computes block b=m-1; B soil
// block b=m-2; C FIR block b=m-3; C stores block b=m-4. NROUND=NBLK+4.
// LDS slots by block parity: writer of parity p at round b+1 (rtpe) /
// b+2 (q); reader at b+2 / b+3; next same-parity write at b+3 / b+4 -> safe.
__global__ __launch_bounds__(192, 1) void hbv_pipe3(const float* __restrict__ xp,
                                                    const float* __restrict__ ps,
                                                    float* __restrict__ out) {
    __shared__ float2 rtpe_buf[2][KB][64];  // A -> B : (rain+tosoil, pet)
    __shared__ float  q_buf[2][KB][64];     // B -> C : q

    const int lane = threadIdx.x & 63;
    const int wid  = threadIdx.x >> 6;
    int g = blockIdx.x * 64 + lane;
    g = (g < NGRID) ? g : (NGRID - 1);      // clamp: dup work, benign
    const int pb = g * 16;
    const F3* __restrict__ xv = (const F3*)xp;

    // ---- role A state ----
    float aTT = 0, aCFMAX = 0, aCFRxCFMAX = 0, aCWH = 0;
    float snow = NEARZERO, melt = NEARZERO;
    F3 abufA[KB], abufB[KB];               // static names only (no runtime idx)
    // ---- role B state ----
    float bFC = 0, bBETA = 0, bB1 = 0, bBETAET = 0, bB2 = 0, bInvFC = 0,
          bC = 0, bPERC = 0, bK0 = 0, bK1 = 0, bK2 = 0, bUZL = 0;
    float sm = NEARZERO, suz = NEARZERO, slz = NEARZERO;
    // ---- role C state ----
    float w[LENF];
    float r[LENF - 1];
    float outv[KB];

    if (wid == 0) {
        aTT        = ps[pb + 8]  * 5.0f - 2.5f;
        aCFMAX     = ps[pb + 9]  * 9.5f + 0.5f;
        aCFRxCFMAX = (ps[pb + 10] * 0.1f) * aCFMAX;
        aCWH       = ps[pb + 11] * 0.2f;
    } else if (wid == 1) {
        bFC     = ps[pb + 1]  * 950.0f + 50.0f;
        bBETA   = ps[pb + 0]  * 5.0f   + 1.0f;
        float LP = ps[pb + 5] * 0.8f   + 0.2f;
        bBETAET = ps[pb + 12] * 4.7f   + 0.3f;
        bInvFC  = 1.0f / bFC;
        // fold the argument scaling into the log: log2(x/FC)=log2(x)-log2(FC)
        bB1 = -bBETA   * __builtin_amdgcn_logf(bFC);
        bB2 = -bBETAET * __builtin_amdgcn_logf(LP * bFC);
        bC   = ps[pb + 13];
        bPERC = ps[pb + 6] * 10.0f;
        bK0  = ps[pb + 2] * 0.85f  + 0.05f;
        bK1  = ps[pb + 3] * 0.49f  + 0.01f;
        bK2  = ps[pb + 4] * 0.199f + 0.001f;
        bUZL = ps[pb + 7] * 100.0f;
    } else {
        // routing weights; -lgamma(aa)-aa*log(theta) cancel under normalization
        const float LOG2E = 1.4426950408889634f;
        float aa    = fmaxf(ps[pb + 14] * 2.9f, 0.0f) + 0.1f;
        float theta = fmaxf(ps[pb + 15] * 6.5f, 0.0f) + 0.5f;
        float sc = LOG2E / theta, am1 = aa - 1.0f, wsum = 0.0f;
#pragma unroll
        for (int k = 0; k < LENF; ++k) {
            float tg = (float)k + 0.5f;
            w[k] = __builtin_amdgcn_exp2f(am1 * __builtin_amdgcn_logf(tg) - tg * sc);
            wsum += w[k];
        }
        float inv = 1.0f / wsum;
#pragma unroll
        for (int k = 0; k < LENF; ++k) w[k] *= inv;
#pragma unroll
        for (int j = 0; j < LENF - 1; ++j) r[j] = 0.0f;
    }

    // batch prefetch of one input block into a register buffer
    auto LOADIN = [&](F3* buf, int blk) {
#pragma unroll
        for (int i = 0; i < KB; ++i)
            buf[i] = xv[(size_t)(blk * KB + i) * NGRID + g];
    };
    // snow chain for one block (consumes a register buffer loaded last round)
    auto SNOW = [&](const F3* in, int b) {
        float2 (*rp)[64] = rtpe_buf[b & 1];
#pragma unroll
        for (int i = 0; i < KB; ++i) {
            float p = in[i].p, tm = in[i].t;
            float dt = tm - aTT;
            float rain = (dt >= 0.0f) ? p : 0.0f;
            float mm = fmaxf(aCFMAX * dt, 0.0f);
            float rr = fmaxf(-aCFRxCFMAX * dt, 0.0f);   // == aCFRxCFMAX*(aTT-tm)
            snow += p - rain;
            float mq = fminf(mm, snow);
            melt += mq; snow -= mq;
            float refr = fminf(rr, melt);
            snow += refr; melt -= refr;
            float tosoil = fmaxf(fmaf(-aCWH, snow, melt), 0.0f);
            melt -= tosoil;
            rp[i][lane] = make_float2(rain + tosoil, in[i].e);
        }
    };

    for (int m = 0; m < NROUND; ++m) {
        if (wid == 0) {
            // section A1: issue next block's 10 loads FIRST (old by barrier)
            if (m < NBLK) {
                if ((m & 1) == 0) LOADIN(abufA, m);
                else              LOADIN(abufB, m);
            }
            __builtin_amdgcn_sched_barrier(0);
            // section A2: snow chain on the block loaded LAST round
            if (m >= 1 && m <= NBLK) {
                int b = m - 1;
                if ((b & 1) == 0) SNOW(abufA, b);
                else              SNOW(abufB, b);
            }
        } else if (wid == 1) {
            if (m >= 2 && m <= NBLK + 1) {
                int b = m - 2, slot = b & 1;
                float rt[KB], pe[KB];
#pragma unroll
                for (int i = 0; i < KB; ++i) {
                    float2 v = rtpe_buf[slot][i][lane];
                    rt[i] = v.x; pe[i] = v.y;
                }
#pragma unroll
                for (int i = 0; i < KB; ++i) {
                    float l1  = __builtin_amdgcn_logf(sm);
                    float sw  = fminf(__builtin_amdgcn_exp2f(fmaf(bBETA, l1, bB1)), 1.0f);
                    float smp = sm + rt[i];
                    float sm1 = fmaf(-rt[i], sw, smp);
                    float rch = rt[i] * sw;
                    float sm2 = fminf(sm1, bFC);
                    float exc = fmaxf(sm1 - bFC, 0.0f);
                    float l2  = __builtin_amdgcn_logf(sm2);
                    float ef  = fminf(__builtin_amdgcn_exp2f(fmaf(bBETAET, l2, bB2)), 1.0f);
                    float sm3 = fmaxf(fmaf(-pe[i], ef, sm2), NEARZERO);
                    float d   = fmaxf(fmaf(-bInvFC, sm3, 1.0f), 0.0f);
                    float cz  = bC * slz;
                    float cap = fminf(slz, cz * d);
                    sm = sm3 + cap;
                    float slz1 = fmaxf(slz - cap, NEARZERO);
                    float su1 = suz + rch + exc;
                    float pa  = fminf(su1, bPERC);
                    float su2 = su1 - pa;
                    float q0  = bK0 * fmaxf(su2 - bUZL, 0.0f);
                    float su3 = su2 - q0;
                    float q1  = bK1 * su3;
                    suz = su3 - q1;
                    float sl2 = slz1 + pa;
                    float q2  = bK2 * sl2;
                    slz = sl2 - q2;
                    q_buf[slot][i][lane] = (q0 + q1) + q2;
                }
            }
        } else {
            // section C1: store LAST round's outputs first (old by barrier)
            if (m >= 4 && m <= NBLK + 3) {
                int bs = m - 4;
#pragma unroll
                for (int i = 0; i < KB; ++i)
                    out[(size_t)(bs * KB + i) * NGRID + g] = outv[i];
            }
            __builtin_amdgcn_sched_barrier(0);
            // section C2: FIR for block m-3 into the register out-buffer
            if (m >= 3 && m <= NBLK + 2) {
                int b = m - 3, slot = b & 1;
                float qv[KB];
#pragma unroll
                for (int i = 0; i < KB; ++i) qv[i] = q_buf[slot][i][lane];
#pragma unroll
                for (int i = 0; i < KB; ++i) {
                    float q = qv[i];
                    outv[i] = fmaf(w[0], q, r[0]);
#pragma unroll
                    for (int j = 0; j < LENF - 2; ++j)
                        r[j] = fmaf(w[j + 1], q, r[j + 1]);
                    r[LENF - 2] = w[LENF - 1] * q;
                }
            }
        }
        __syncthreads();
    }
}

extern "C" void kernel_launch(void* const* d_in, const int* in_sizes, int n_in,
                              void* d_out, int out_size, void* d_ws, size_t ws_size,
                              hipStream_t stream) {
    const float* x_phy      = (const float*)d_in[0]; // f32 (730,10000,3)
    const float* phy_static = (const float*)d_in[1]; // f32 (10000,16)
    float* out = (float*)d_out;                      // f32 (730,10000)

    int nwg = (NGRID + 63) / 64;  // 157 workgroups x 192 threads (3 waves)
    hbv_pipe3<<<nwg, 192, 0, stream>>>(x_phy, phy_static, out);
}